// Round 5
// baseline (164.697 us; speedup 1.0000x reference)
//
#include <hip/hip_runtime.h>
#include <hip/hip_bf16.h>
#include <math.h>

#define HW 6400
#define NT 256
#define PT 25        // elements per thread
#define NB 2048      // value buckets
#define BPT (NB/NT)  // buckets per thread (8)
#define R 4          // rows per block

// Barrier that does NOT drain vmcnt: LDS ops complete (lgkmcnt), global
// prefetch loads stay in flight across the barrier (T4-style).
__device__ __forceinline__ void light_barrier() {
  asm volatile("s_waitcnt lgkmcnt(0)" ::: "memory");
  __builtin_amdgcn_s_barrier();
  __builtin_amdgcn_sched_barrier(0);
}

// Writes the 7 outputs of previous row PR (parity Q) from s_pref[Q] + regs.
#define RESOLVE(Q, PR)                                                        \
  if (tid < 7) {                                                              \
    int gp = row0 + (PR);                                                     \
    float* db = stacked + ((size_t)(gp >> 9) * 7) * 512 + (gp & 511);         \
    if (tid == 5) db[0] = tot##Q * (1.f / 6400.f);                            \
    else if (tid == 6) db[512] = gmx##Q;                                      \
    else if (tid < 4) {                                                       \
      double w = (double)(gmx##Q - gmn##Q) * (1.0 / (double)NB);              \
      float Xm = (tid == 0) ? 0.f : s_pref[Q][tid - 1];                       \
      double bin = (double)gmn##Q +                                           \
                   w * (double)(s_pref[Q][tid] - Xm) * (1.0 / 1280.0);        \
      db[(size_t)(2 + tid) * 512] = (float)bin;                               \
    } else {                                                                  \
      double w = (double)(gmx##Q - gmn##Q) * (1.0 / (double)NB);              \
      double bin = ((double)tot##Q -                                          \
                    ((double)gmn##Q * 5120.0 + w * (double)s_pref[Q][3])) *   \
                   (1.0 / 1280.0);                                            \
      db[(size_t)6 * 512] = (float)bin;                                       \
    }                                                                         \
  }

// Process one row held in VC (parity P); prefetch next row into VN; resolve
// previous row (parity Q) under this row's compute.
#define BODY(VC, VN, P, Q, RIDX)                                              \
  {                                                                           \
    float lmx = VC[0], lmn = VC[0], lsm = VC[0];                              \
    _Pragma("unroll") for (int i = 1; i < PT; ++i) {                          \
      lmx = fmaxf(lmx, VC[i]); lmn = fminf(lmn, VC[i]); lsm += VC[i];         \
    }                                                                         \
    _Pragma("unroll") for (int off = 32; off; off >>= 1) {                    \
      lmx = fmaxf(lmx, __shfl_down(lmx, off));                                \
      lmn = fminf(lmn, __shfl_down(lmn, off));                                \
      lsm += __shfl_down(lsm, off);                                           \
    }                                                                         \
    if (lane == 0) {                                                          \
      s_part[P][0][wid] = lmn; s_part[P][1][wid] = lmx; s_part[P][2][wid] = lsm; \
    }                                                                         \
    light_barrier(); /* B1: partials + hist[P] zero visible */                \
    gmn##P = fminf(fminf(s_part[P][0][0], s_part[P][0][1]),                   \
                   fminf(s_part[P][0][2], s_part[P][0][3]));                  \
    gmx##P = fmaxf(fmaxf(s_part[P][1][0], s_part[P][1][1]),                   \
                   fmaxf(s_part[P][1][2], s_part[P][1][3]));                  \
    tot##P = (s_part[P][2][0] + s_part[P][2][1]) +                            \
             (s_part[P][2][2] + s_part[P][2][3]);                             \
    if (RIDX > 0) { RESOLVE(Q, RIDX - 1); }                                   \
    {                                                                         \
      float d = gmx##P - gmn##P;                                              \
      float scale = d > 0.f ? (float)NB / d : 0.f;                            \
      float nls = -gmn##P * scale;                                            \
      _Pragma("unroll") for (int i = 0; i < PT; ++i) {                        \
        float f = fmaf(VC[i], scale, nls);                                    \
        f = fminf(fmaxf(f, 0.f), (float)(NB - 1));                            \
        atomicAdd(&s_hist[P][(int)f], 1u);                                    \
      }                                                                       \
    }                                                                         \
    if (RIDX + 1 < R) { /* prefetch next row; stays in flight past barriers */\
      const float4* xp = (const float4*)(x + (size_t)(row0 + RIDX + 1) * HW); \
      _Pragma("unroll") for (int j = 0; j < 6; ++j) {                         \
        float4 q4 = xp[tid + j * NT];                                         \
        VN[4 * j] = q4.x; VN[4 * j + 1] = q4.y;                               \
        VN[4 * j + 2] = q4.z; VN[4 * j + 3] = q4.w;                           \
      }                                                                       \
      VN[24] = ((const float*)xp)[6144 + tid];                                \
    }                                                                         \
    light_barrier(); /* B2: atomics done */                                   \
    {                                                                         \
      unsigned hh[BPT];                                                       \
      const uint4* pp = (const uint4*)&s_hist[P][tid * BPT];                  \
      uint4 a4 = pp[0], b4 = pp[1];                                           \
      hh[0] = a4.x; hh[1] = a4.y; hh[2] = a4.z; hh[3] = a4.w;                 \
      hh[4] = b4.x; hh[5] = b4.y; hh[6] = b4.z; hh[7] = b4.w;                 \
      unsigned long long run = 0ULL;                                          \
      _Pragma("unroll") for (int j = 0; j < BPT; ++j)                         \
        run += ((unsigned long long)hh[j] << 32) |                            \
               (unsigned long long)(hh[j] * (unsigned)(tid * BPT + j));       \
      unsigned long long inc = run;                                           \
      _Pragma("unroll") for (int off = 1; off < 64; off <<= 1) {              \
        unsigned long long uu = __shfl_up(inc, off);                          \
        if (lane >= off) inc += uu;                                           \
      }                                                                       \
      if (lane == 63) s_wtot[P][wid] = inc;                                   \
      { /* zero other hist for row RIDX+1 */                                  \
        uint4* zz = (uint4*)&s_hist[Q][tid * BPT];                            \
        zz[0] = make_uint4(0u, 0u, 0u, 0u);                                   \
        zz[1] = make_uint4(0u, 0u, 0u, 0u);                                   \
      }                                                                       \
      light_barrier(); /* B3: wave totals visible */                          \
      unsigned long long E = inc - run;                                       \
      _Pragma("unroll") for (int w = 0; w < 4; ++w)                           \
        if (w < wid) E += s_wtot[P][w];                                       \
      _Pragma("unroll") for (int j = 0; j < BPT; ++j) {                       \
        unsigned long long dlt =                                              \
            ((unsigned long long)hh[j] << 32) |                               \
            (unsigned long long)(hh[j] * (unsigned)(tid * BPT + j));          \
        unsigned long long I = E + dlt;                                       \
        unsigned cEc = (unsigned)(E >> 32), cIc = (unsigned)(I >> 32);        \
        _Pragma("unroll") for (int t = 0; t < 4; ++t) {                       \
          unsigned k = 1280u * (t + 1);                                       \
          if (cEc < k && k <= cIc) {                                          \
            float m = (float)(k - cEc);                                       \
            float X = (float)(unsigned)(E & 0xFFFFFFFFu) +                    \
                      0.5f * (float)cEc +                                     \
                      m * ((float)(tid * BPT + j) + 0.5f);                    \
            s_pref[P][t] = X;                                                 \
          }                                                                   \
        }                                                                     \
        E = I;                                                                \
      }                                                                       \
    }                                                                         \
  }

// 4 rows per block, register-double-buffered prefetch, ping-pong histograms,
// light barriers (loads in flight across barriers).
__global__ __launch_bounds__(NT, 5) void rowstats_kernel(
    const float* __restrict__ x, float* __restrict__ stacked) {
  const int tid = threadIdx.x;
  const int lane = tid & 63;
  const int wid = tid >> 6;
  const int row0 = blockIdx.x * R;

  __shared__ unsigned s_hist[2][NB];       // 16 KB ping-pong
  __shared__ float s_part[2][3][4];        // per-wave min/max/sum
  __shared__ unsigned long long s_wtot[2][4];
  __shared__ float s_pref[2][4];           // weighted-index prefix X_t

  float vA[PT], vB[PT];
  float gmn0, gmx0, tot0, gmn1, gmx1, tot1;
  gmn1 = gmx1 = tot1 = 0.f;  // silence uninit for RIDX=0 path (dead)

  // Prologue: load row0 into vA; zero hist[0].
  {
    const float4* xp = (const float4*)(x + (size_t)row0 * HW);
#pragma unroll
    for (int j = 0; j < 6; ++j) {
      float4 q4 = xp[tid + j * NT];
      vA[4 * j] = q4.x; vA[4 * j + 1] = q4.y;
      vA[4 * j + 2] = q4.z; vA[4 * j + 3] = q4.w;
    }
    vA[24] = ((const float*)xp)[6144 + tid];
    uint4* zz = (uint4*)&s_hist[0][tid * BPT];
    zz[0] = make_uint4(0u, 0u, 0u, 0u);
    zz[1] = make_uint4(0u, 0u, 0u, 0u);
  }

  BODY(vA, vB, 0, 1, 0);
  BODY(vB, vA, 1, 0, 1);
  BODY(vA, vB, 0, 1, 2);
  BODY(vB, vA, 1, 0, 3);

  light_barrier();
  RESOLVE(1, R - 1);
}

// One block per batch element: h = relu(stacked @ W1^T); g = sum_n w7[n]*h[n];
// out[c] = sigmoid(dot(g, W2[c,:]) + bias)
__global__ __launch_bounds__(256) void mlp_kernel(
    const float* __restrict__ stacked, const float* __restrict__ W1,
    const float* __restrict__ W2, const float* __restrict__ w7,
    const float* __restrict__ bias, float* __restrict__ out) {
  const int b = blockIdx.x;
  const int tid = threadIdx.x;
  __shared__ float s_stk[7 * 512];
  __shared__ float s_g[32];
  const float* src = stacked + (size_t)b * 7 * 512;
  for (int i = tid; i < 7 * 512; i += 256) s_stk[i] = src[i];
  if (tid < 32) s_g[tid] = 0.f;
  __syncthreads();
  if (tid < 224) {
    const int n = tid >> 5, r = tid & 31;
    float acc = 0.f;
    for (int c = 0; c < 512; ++c) acc = fmaf(s_stk[n * 512 + c], W1[r * 512 + c], acc);
    acc = fmaxf(acc, 0.f);
    atomicAdd(&s_g[r], w7[n] * acc);
  }
  __syncthreads();
  const float bv = bias[0];
  for (int c = tid; c < 512; c += 256) {
    float acc = bv;
#pragma unroll
    for (int r = 0; r < 32; ++r) acc = fmaf(s_g[r], W2[c * 32 + r], acc);
    out[b * 512 + c] = 1.f / (1.f + expf(-acc));
  }
}

extern "C" void kernel_launch(void* const* d_in, const int* in_sizes, int n_in,
                              void* d_out, int out_size, void* d_ws, size_t ws_size,
                              hipStream_t stream) {
  const float* x = (const float*)d_in[0];
  const float* W1 = (const float*)d_in[1];
  const float* W2 = (const float*)d_in[2];
  const float* w7 = (const float*)d_in[3];
  const float* bb = (const float*)d_in[4];
  float* out = (float*)d_out;
  float* stacked = (float*)d_ws;  // 32*7*512*4 = 458752 bytes

  rowstats_kernel<<<(32 * 512) / R, NT, 0, stream>>>(x, stacked);
  mlp_kernel<<<32, 256, 0, stream>>>(stacked, W1, W2, w7, bb, out);
}